// Round 2
// baseline (1380.407 us; speedup 1.0000x reference)
//
#include <hip/hip_runtime.h>
#include <math.h>

typedef _Float16 half8 __attribute__((ext_vector_type(8)));
typedef float float4v __attribute__((ext_vector_type(4)));

constexpr int Lc   = 2048;  // L_IN
constexpr int DECc = 64;    // DEC_LEN
constexpr int Hc   = 128;   // H
constexpr int EMBc = 16;    // EMB
constexpr int INc  = 18;    // IN_SIZE
constexpr int NBc  = 4;     // batches per block
constexpr int NTc  = 512;   // 8 waves
constexpr int CARD = 200;
constexpr int ZS   = 160;   // z stride per batch (halves); 320B -> 2-way (free) on b128 reads

// z layout (per batch, K-position): k=0..127 h (recurrent), k=128..145 x (non-recurrent,
// never materialized in LDS -- fed via register A-frag acc_pre), k=146..159 pad.

__device__ __forceinline__ float rcp_(float x) { return __builtin_amdgcn_rcpf(x); }
__device__ __forceinline__ float sigm(float x) { return rcp_(1.0f + __expf(-x)); }
__device__ __forceinline__ float tanh_(float x) { return 2.0f * rcp_(1.0f + __expf(-2.0f * x)) - 1.0f; }
__device__ __forceinline__ float softplus_(float x) { return __logf(1.0f + __expf(x)); }

// dynamic 4-element select (3 cndmask)
__device__ __forceinline__ float sel4(float4v v, int q) {
    const float a = (q & 1) ? v[1] : v[0];
    const float b = (q & 1) ? v[3] : v[2];
    return (q & 2) ? b : a;
}

// Gate-type-per-accumulator layout (no shuffle):
//   wave wv owns cells 16wv..16wv+15; acc[gt] = gates of type gt for those cells.
// A-frag (z): lane holds A[m=col][k=quad*8+j], A[m] = z[batch m&3]  (batches replicated)
// B-frag:     lane holds B[k][n=col], B[k][n] = W[gt*128 + 16wv+col][k]  (h-first K order)
// C: col = cell-local, reg r = batch -> lane (q,col) keeps batch q via sel4.

__global__ __launch_bounds__(NTc, 1) void rnnar_kernel(
    const int*   __restrict__ cat_in,  const float* __restrict__ cont_in,
    const float* __restrict__ X_in,    const int*   __restrict__ cat_out,
    const float* __restrict__ cont_out,const float* __restrict__ emb_table,
    const float* __restrict__ cont_w,
    const float* __restrict__ Wih_e, const float* __restrict__ Whh_e, const float* __restrict__ b_e,
    const float* __restrict__ Wih_d, const float* __restrict__ Whh_d, const float* __restrict__ b_d,
    const float* __restrict__ Wm, const float* __restrict__ bm,
    const float* __restrict__ Ws, const float* __restrict__ bs,
    const float* __restrict__ Wv, const float* __restrict__ bv,
    float* __restrict__ out)
{
    __shared__ _Float16      z_lds[2][NBc * ZS];   // 2.5 KB double-buffered h, [b][k]
    __shared__ _Float16      emb_lds[CARD * EMBc]; // 6.4 KB
    __shared__ _Float16      xs0[NBc * Lc];        // 16 KB cont_in * w00
    __shared__ _Float16      xs1[NBc * Lc];        // 16 KB X_in
    __shared__ _Float16      xo_lds[NBc * DECc];   // 512 B cont_out * w00
    __shared__ unsigned char catb[NBc * Lc];       // 8 KB
    __shared__ unsigned char catob[NBc * DECc];    // 256 B
    __shared__ float         h32_lds[NBc * 132];   // 2.1 KB
    __shared__ float         wh_lds[6 * Hc];       // 3 KB
    __shared__ float         hb_lds[8];
    __shared__ float         mu_lds[4];            // decoder mu feedback (rank-1 correction)

    const int tid  = threadIdx.x;
    const int lane = tid & 63;
    const int wv   = tid >> 6;        // wave 0..7
    const int q    = lane >> 4;       // quad 0..3 = this lane's batch
    const int col  = lane & 15;       // cell-local 0..15
    const int cell = 16 * wv + col;   // this lane's cell
    const int bx   = col & 3;         // A-frag batch
    const int b0   = blockIdx.x * NBc;
    const float w00 = cont_w[0];

    // ---------------- staging ----------------
    {
        int* z32 = (int*)&z_lds[0][0];
        for (int i = tid; i < NBc * ZS; i += NTc) z32[i] = 0;  // both buffers
    }
    for (int i = tid; i < NBc * Lc; i += NTc) {
        const int b = i >> 11, t = i & (Lc - 1);
        catb[i] = (unsigned char)cat_in[(b0 + b) * Lc + t];
        xs0[i]  = (_Float16)(cont_in[(b0 + b) * Lc + t] * w00);
        xs1[i]  = (_Float16)(X_in[(b0 + b) * Lc + t]);
    }
    if (tid < NBc * DECc) {
        const int b = tid >> 6, t = tid & 63;
        catob[tid]  = (unsigned char)cat_out[(b0 + b) * DECc + t];
        xo_lds[tid] = (_Float16)(cont_out[(b0 + b) * DECc + t] * w00);
    }
    for (int i = tid; i < CARD * EMBc; i += NTc) emb_lds[i] = (_Float16)emb_table[i];
    for (int i = tid; i < 6 * Hc; i += NTc) {
        const int o = i >> 7, k = i & 127;
        wh_lds[i] = (o == 0) ? Wm[k] : (o == 1) ? Ws[k] : Wv[(o - 2) * Hc + k];
    }
    if (tid == 0) { hb_lds[0] = bm[0]; hb_lds[1] = bs[0]; }
    if (tid < 4)  { hb_lds[2 + tid] = bv[tid]; mu_lds[tid] = 0.0f; }

    // ---- B-fragments: acc tile index == gate type; h-first K order ----
    half8 Bf[4][5];
    float bias_s[4];
    float w17_s[4];   // Wih[row][17] -- decoder mu rank-1 column
    #define LOAD_T(WIH, WHH, BB)                                               \
    {                                                                          \
        _Pragma("unroll")                                                      \
        for (int gt = 0; gt < 4; ++gt) {                                       \
            const int row = gt * Hc + cell;                                    \
            _Pragma("unroll")                                                  \
            for (int kt = 0; kt < 5; ++kt) {                                   \
                half8 f;                                                       \
                _Pragma("unroll")                                              \
                for (int j = 0; j < 8; ++j) {                                  \
                    const int k = 32 * kt + 8 * q + j;                         \
                    float v = 0.0f;                                            \
                    if (k < Hc)             v = WHH[row * Hc + k];             \
                    else if (k < Hc + INc)  v = WIH[row * INc + (k - Hc)];     \
                    f[j] = (_Float16)v;                                        \
                }                                                              \
                Bf[gt][kt] = f;                                                \
            }                                                                  \
            bias_s[gt] = BB[row];                                              \
            w17_s[gt]  = WIH[row * INc + 17];                                  \
        }                                                                      \
    }

    LOAD_T(Wih_e, Whh_e, b_e);
    __syncthreads();

    float4v acc_pre[4];  // bias + x-part contribution for the NEXT step, per gate

    // x A-frag builder (encoder): slots 0..15 emb, 16 cont, 17 X, rest pad
    #define PRE_ENC(T1)                                                        \
    {                                                                          \
        const int t1 = (T1);                                                   \
        half8 ax;                                                              \
        _Pragma("unroll") for (int j = 0; j < 8; ++j) ax[j] = (_Float16)0.0f;  \
        if (q < 2)       ax = *(const half8*)&emb_lds[(int)catb[bx * Lc + t1] * EMBc + 8 * q]; \
        else if (q == 2) { ax[0] = xs0[bx * Lc + t1]; ax[1] = xs1[bx * Lc + t1]; } \
        _Pragma("unroll")                                                      \
        for (int gt = 0; gt < 4; ++gt) {                                       \
            float4v a = {bias_s[gt], bias_s[gt], bias_s[gt], bias_s[gt]};      \
            acc_pre[gt] = __builtin_amdgcn_mfma_f32_16x16x32_f16(ax, Bf[gt][4], a, 0, 0, 0); \
        }                                                                      \
    }

    PRE_ENC(0);          // x(0)

    int p = 0;
    float c_reg = 0.f;

    // ===================== encoder: 1 barrier/step =====================
    for (int t = 0; t < Lc; ++t) {
        const _Float16* zr = &z_lds[p][0];
        _Float16*       zw = &z_lds[p ^ 1][0];

        // h A-frags (k-tiles 0..3)
        const _Float16* ap = zr + bx * ZS + 8 * q;
        half8 Az[4];
        #pragma unroll
        for (int kt = 0; kt < 4; ++kt) Az[kt] = *(const half8*)(ap + 32 * kt);

        float4v acc[4];
        #pragma unroll
        for (int gt = 0; gt < 4; ++gt) {
            float4v a = acc_pre[gt];
            #pragma unroll
            for (int kt = 0; kt < 4; ++kt)
                a = __builtin_amdgcn_mfma_f32_16x16x32_f16(Az[kt], Bf[gt][kt], a, 0, 0, 0);
            acc[gt] = a;
        }

        // precompute x(t+1) contribution (off critical path; clamp for t=Lc-1, redone below)
        PRE_ENC((t + 1 < Lc) ? t + 1 : Lc - 1);

        const float gi = sel4(acc[0], q);
        const float gf = sel4(acc[1], q);
        const float gg = sel4(acc[2], q);
        const float go = sel4(acc[3], q);

        const float cn = sigm(gf) * c_reg + sigm(gi) * tanh_(gg);
        c_reg = cn;
        zw[q * ZS + cell] = (_Float16)(sigm(go) * tanh_(cn));

        __syncthreads();
        p ^= 1;
    }

    // ===================== decoder =====================
    LOAD_T(Wih_d, Whh_d, b_d);
    const float bm0 = hb_lds[0], bs0 = hb_lds[1];

    // decoder step 0 x = [emb(cat_in last), cont_in last, X_in last] with DECODER weights
    {
        const int t1 = Lc - 1;
        half8 ax;
        #pragma unroll
        for (int j = 0; j < 8; ++j) ax[j] = (_Float16)0.0f;
        if (q < 2)       ax = *(const half8*)&emb_lds[(int)catb[bx * Lc + t1] * EMBc + 8 * q];
        else if (q == 2) { ax[0] = xs0[bx * Lc + t1]; ax[1] = xs1[bx * Lc + t1]; }
        #pragma unroll
        for (int gt = 0; gt < 4; ++gt) {
            float4v a = {bias_s[gt], bias_s[gt], bias_s[gt], bias_s[gt]};
            acc_pre[gt] = __builtin_amdgcn_mfma_f32_16x16x32_f16(ax, Bf[gt][4], a, 0, 0, 0);
        }
    }
    __syncthreads();   // mu_lds (=0) + decoder state visible

    for (int t = 0; t < DECc; ++t) {
        const _Float16* zr = &z_lds[p][0];
        _Float16*       zw = &z_lds[p ^ 1][0];

        const float muq = mu_lds[q];   // mu(t-1) for this lane's batch (0 at t=0)

        const _Float16* ap = zr + bx * ZS + 8 * q;
        half8 Az[4];
        #pragma unroll
        for (int kt = 0; kt < 4; ++kt) Az[kt] = *(const half8*)(ap + 32 * kt);

        float4v acc[4];
        #pragma unroll
        for (int gt = 0; gt < 4; ++gt) {
            float4v a = acc_pre[gt];
            #pragma unroll
            for (int kt = 0; kt < 4; ++kt)
                a = __builtin_amdgcn_mfma_f32_16x16x32_f16(Az[kt], Bf[gt][kt], a, 0, 0, 0);
            acc[gt] = a;
        }

        // precompute x(t+1) = [emb(cat_out t), cont_out t, mu(t)] -- mu folded in next step
        {
            half8 ax;
            #pragma unroll
            for (int j = 0; j < 8; ++j) ax[j] = (_Float16)0.0f;
            if (q < 2)       ax = *(const half8*)&emb_lds[(int)catob[bx * DECc + t] * EMBc + 8 * q];
            else if (q == 2) ax[0] = xo_lds[bx * DECc + t];
            #pragma unroll
            for (int gt = 0; gt < 4; ++gt) {
                float4v a = {bias_s[gt], bias_s[gt], bias_s[gt], bias_s[gt]};
                acc_pre[gt] = __builtin_amdgcn_mfma_f32_16x16x32_f16(ax, Bf[gt][4], a, 0, 0, 0);
            }
        }

        // gates with mu rank-1 correction
        const float gi = sel4(acc[0], q) + muq * w17_s[0];
        const float gf = sel4(acc[1], q) + muq * w17_s[1];
        const float gg = sel4(acc[2], q) + muq * w17_s[2];
        const float go = sel4(acc[3], q) + muq * w17_s[3];

        const float cn = sigm(gf) * c_reg + sigm(gi) * tanh_(gg);
        c_reg = cn;
        const float hv = sigm(go) * tanh_(cn);
        zw[q * ZS + cell] = (_Float16)hv;
        h32_lds[q * 132 + cell] = hv;

        __syncthreads();

        // heads: 24 dot-products x 16 lanes each (8 strided FMAs + shfl reduce)
        if (tid < 384) {
            const int grp = tid >> 4;       // 0..23, wave-aligned 16-thread groups
            const int l16 = tid & 15;
            const int b   = grp & 3, o = grp >> 2;  // o = 0..5
            float s = 0.0f;
            #pragma unroll
            for (int j = 0; j < 8; ++j) {
                const int k = l16 + 16 * j;
                s += wh_lds[o * Hc + k] * h32_lds[b * 132 + k];
            }
            s += __shfl_xor(s, 1);
            s += __shfl_xor(s, 2);
            s += __shfl_xor(s, 4);
            s += __shfl_xor(s, 8);
            if (l16 == 0) {
                const int gb = b0 + b;
                if (o == 0) {
                    const float mu = s + bm0;
                    out[gb * DECc + t] = mu;
                    mu_lds[b] = mu;   // feedback for rank-1 correction next step
                } else if (o == 1) {
                    out[65536 + gb * DECc + t] = softplus_(s + bs0);
                } else {
                    out[131072 + (gb * DECc + t) * 4 + (o - 2)] = s + hb_lds[2 + (o - 2)];
                }
            }
        }
        __syncthreads();
        p ^= 1;
    }
    #undef LOAD_T
    #undef PRE_ENC
}

extern "C" void kernel_launch(void* const* d_in, const int* in_sizes, int n_in,
                              void* d_out, int out_size, void* d_ws, size_t ws_size,
                              hipStream_t stream) {
    rnnar_kernel<<<1024 / NBc, NTc, 0, stream>>>(
        (const int*)d_in[0],   (const float*)d_in[1],  (const float*)d_in[2],
        (const int*)d_in[3],   (const float*)d_in[4],  (const float*)d_in[5],
        (const float*)d_in[6],
        (const float*)d_in[7], (const float*)d_in[8],  (const float*)d_in[9],
        (const float*)d_in[10],(const float*)d_in[11], (const float*)d_in[12],
        (const float*)d_in[13],(const float*)d_in[14],
        (const float*)d_in[15],(const float*)d_in[16],
        (const float*)d_in[17],(const float*)d_in[18],
        (float*)d_out);
}

// Round 3
// 1244.453 us; speedup vs baseline: 1.1092x; 1.1092x over previous
//
#include <hip/hip_runtime.h>
#include <math.h>

typedef _Float16 half8 __attribute__((ext_vector_type(8)));
typedef float float4v __attribute__((ext_vector_type(4)));

constexpr int Lc   = 2048;  // L_IN
constexpr int DECc = 64;    // DEC_LEN
constexpr int Hc   = 128;   // H
constexpr int EMBc = 16;    // EMB
constexpr int INc  = 18;    // IN_SIZE
constexpr int NBc  = 4;     // batches per block
constexpr int NTc  = 512;   // 8 waves
constexpr int CARD = 200;
constexpr int ZS   = 160;   // z stride per batch (halves); 320B keeps b128 reads 2-way (free)

// z holds ONLY h (k=0..127). The x-part (K=18) is computed out-of-band:
// encoder: one 4-MFMA group per 4 steps packs timesteps T..T+3 into the padded
// M rows (A[m=4u+b] = x_{T+u}[b]); results (bias + Wih.x, f32) parked in a
// 4-slot wave-local LDS ring, prefetched 1 step ahead as the MFMA C-init.
// decoder: per-step x build (64 steps only), mu fed back as a rank-1 w17 term.

__device__ __forceinline__ float rcp_(float x) { return __builtin_amdgcn_rcpf(x); }
__device__ __forceinline__ float sigm(float x) { return rcp_(1.0f + __expf(-x)); }
__device__ __forceinline__ float tanh_(float x) { return 2.0f * rcp_(1.0f + __expf(-2.0f * x)) - 1.0f; }
__device__ __forceinline__ float softplus_(float x) { return __logf(1.0f + __expf(x)); }

// dynamic 4-element select (3 cndmask)
__device__ __forceinline__ float sel4(float4v v, int q) {
    const float a = (q & 1) ? v[1] : v[0];
    const float b = (q & 1) ? v[3] : v[2];
    return (q & 2) ? b : a;
}

__global__ __launch_bounds__(NTc, 1) void rnnar_kernel(
    const int*   __restrict__ cat_in,  const float* __restrict__ cont_in,
    const float* __restrict__ X_in,    const int*   __restrict__ cat_out,
    const float* __restrict__ cont_out,const float* __restrict__ emb_table,
    const float* __restrict__ cont_w,
    const float* __restrict__ Wih_e, const float* __restrict__ Whh_e, const float* __restrict__ b_e,
    const float* __restrict__ Wih_d, const float* __restrict__ Whh_d, const float* __restrict__ b_d,
    const float* __restrict__ Wm, const float* __restrict__ bm,
    const float* __restrict__ Ws, const float* __restrict__ bs,
    const float* __restrict__ Wv, const float* __restrict__ bv,
    float* __restrict__ out)
{
    __shared__ _Float16      z_lds[2][NBc * ZS];     // 2.5 KB double-buffered h
    __shared__ _Float16      emb_lds[CARD * EMBc];   // 6.4 KB
    __shared__ _Float16      xo4[DECc * NBc];        // 512 B  [t][b] cont_out*w00
    __shared__ unsigned char catob4[DECc * NBc];     // 256 B  [t][b]
    __shared__ float         h32_lds[NBc * 132];     // 2.1 KB
    __shared__ float         wh_lds[6 * Hc];         // 3 KB
    __shared__ float         hb_lds[8];
    __shared__ float         mu_lds[4];
    __shared__ float4v       x_lds[8][4][4][16];     // 32 KB [wave][slot][gt][col] = {b0..b3}

    const int tid  = threadIdx.x;
    const int lane = tid & 63;
    const int wv   = tid >> 6;        // wave 0..7
    const int q    = lane >> 4;       // quad 0..3 = this lane's batch (activations)
    const int col  = lane & 15;       // cell-local 0..15
    const int cell = 16 * wv + col;   // this lane's cell
    const int bx   = col & 3;         // A-frag batch (per-step decoder build)
    const int gu   = col >> 2;        // group build: timestep offset 0..3
    const int gb   = col & 3;         // group build: batch
    const int b0   = blockIdx.x * NBc;
    const float w00 = cont_w[0];

    // ---------------- staging ----------------
    {
        int* z32 = (int*)&z_lds[0][0];
        for (int i = tid; i < NBc * ZS; i += NTc) z32[i] = 0;  // both buffers
    }
    for (int i = tid; i < CARD * EMBc; i += NTc) emb_lds[i] = (_Float16)emb_table[i];
    if (tid < NBc * DECc) {  // [t][b] interleave -> broadcast-friendly reads
        const int t = tid >> 2, b = tid & 3;
        catob4[tid] = (unsigned char)cat_out[(b0 + b) * DECc + t];
        xo4[tid]    = (_Float16)(cont_out[(b0 + b) * DECc + t] * w00);
    }
    for (int i = tid; i < 6 * Hc; i += NTc) {
        const int o = i >> 7, k = i & 127;
        wh_lds[i] = (o == 0) ? Wm[k] : (o == 1) ? Ws[k] : Wv[(o - 2) * Hc + k];
    }
    if (tid == 0) { hb_lds[0] = bm[0]; hb_lds[1] = bs[0]; }
    if (tid < 4)  { hb_lds[2 + tid] = bv[tid]; mu_lds[tid] = 0.0f; }

    // ---- B-fragments: acc tile index == gate type; h-first K order ----
    half8 Bf[4][5];
    float bias_s[4];
    float w17_s[4];   // Wih[row][17] -- decoder mu rank-1 column
    #define LOAD_T(WIH, WHH, BB)                                               \
    {                                                                          \
        _Pragma("unroll")                                                      \
        for (int gt = 0; gt < 4; ++gt) {                                       \
            const int row = gt * Hc + cell;                                    \
            _Pragma("unroll")                                                  \
            for (int kt = 0; kt < 5; ++kt) {                                   \
                half8 f;                                                       \
                _Pragma("unroll")                                              \
                for (int j = 0; j < 8; ++j) {                                  \
                    const int k = 32 * kt + 8 * q + j;                         \
                    float v = 0.0f;                                            \
                    if (k < Hc)             v = WHH[row * Hc + k];             \
                    else if (k < Hc + INc)  v = WIH[row * INc + (k - Hc)];     \
                    f[j] = (_Float16)v;                                        \
                }                                                              \
                Bf[gt][kt] = f;                                                \
            }                                                                  \
            bias_s[gt] = BB[row];                                              \
            w17_s[gt]  = WIH[row * INc + 17];                                  \
        }                                                                      \
    }

    // group-build: from g_cat/g_cont/g_X regs -> 4 MFMAs -> x_lds[wv][q][gt][col]
    // lane (q,col) supplies A[m=col][k=8q+j] with x vector chosen by col=(u,b);
    // C rows 4q+r -> lane (q,col) holds timestep T+q, batches r=0..3.
    #define BUILD_X(GCAT, GCONT, GX)                                           \
    {                                                                          \
        half8 ax;                                                              \
        _Pragma("unroll") for (int j = 0; j < 8; ++j) ax[j] = (_Float16)0.0f;  \
        if (q < 2)       ax = *(const half8*)&emb_lds[(GCAT) * EMBc + 8 * q];  \
        else if (q == 2) { ax[0] = (_Float16)((GCONT) * w00); ax[1] = (_Float16)(GX); } \
        _Pragma("unroll")                                                      \
        for (int gt = 0; gt < 4; ++gt) {                                       \
            float4v a = {bias_s[gt], bias_s[gt], bias_s[gt], bias_s[gt]};      \
            a = __builtin_amdgcn_mfma_f32_16x16x32_f16(ax, Bf[gt][4], a, 0, 0, 0); \
            x_lds[wv][q][gt][col] = a;                                         \
        }                                                                      \
    }

    LOAD_T(Wih_e, Whh_e, b_e);
    __syncthreads();

    // prologue: build group 0 (T=0), prefetch slot 0
    int   g_cat;  float g_cont, g_X;
    {
        const long idx = (long)(b0 + gb) * Lc + gu;   // t1 = 0 + gu
        g_cat  = cat_in[idx];
        g_cont = cont_in[idx];
        g_X    = X_in[idx];
    }
    BUILD_X(g_cat, g_cont, g_X);

    float4v xinit[4];
    #pragma unroll
    for (int gt = 0; gt < 4; ++gt) xinit[gt] = x_lds[wv][0][gt][col];

    int p = 0;
    float c_reg = 0.f;

    // ===================== encoder: 1 barrier/step, 16 on-chain MFMAs =====================
    for (int t = 0; t < Lc; ++t) {
        const _Float16* zr = &z_lds[p][0];
        _Float16*       zw = &z_lds[p ^ 1][0];

        // h A-frags (k-tiles 0..3)
        const _Float16* ap = zr + bx * ZS + 8 * q;
        half8 Az[4];
        #pragma unroll
        for (int kt = 0; kt < 4; ++kt) Az[kt] = *(const half8*)(ap + 32 * kt);

        float4v acc[4];
        #pragma unroll
        for (int gt = 0; gt < 4; ++gt) {
            float4v a = xinit[gt];
            #pragma unroll
            for (int kt = 0; kt < 4; ++kt)
                a = __builtin_amdgcn_mfma_f32_16x16x32_f16(Az[kt], Bf[gt][kt], a, 0, 0, 0);
            acc[gt] = a;
        }

        // group pipeline: issue globals at t%4==2, build+store at t%4==3 (2-step slack)
        if ((t & 3) == 2 && t + 2 < Lc) {
            const long idx = (long)(b0 + gb) * Lc + (t + 2 + gu);
            g_cat  = cat_in[idx];
            g_cont = cont_in[idx];
            g_X    = X_in[idx];
        }
        if ((t & 3) == 3 && t + 1 < Lc) BUILD_X(g_cat, g_cont, g_X);

        // prefetch next step's C-init (wave-local, broadcast, in-order after build)
        {
            const int sn = (t + 1) & 3;
            #pragma unroll
            for (int gt = 0; gt < 4; ++gt) xinit[gt] = x_lds[wv][sn][gt][col];
        }

        // gates land in-lane: batch q, cell = 16wv+col
        const float gi = sel4(acc[0], q);
        const float gf = sel4(acc[1], q);
        const float gg = sel4(acc[2], q);
        const float go = sel4(acc[3], q);

        const float cn = sigm(gf) * c_reg + sigm(gi) * tanh_(gg);
        c_reg = cn;
        zw[q * ZS + cell] = (_Float16)(sigm(go) * tanh_(cn));

        __syncthreads();
        p ^= 1;
    }

    // ===================== decoder =====================
    LOAD_T(Wih_d, Whh_d, b_d);
    const float bm0 = hb_lds[0], bs0 = hb_lds[1];

    float4v acc_pre[4];
    // decoder x(0) = [emb(cat_in last), cont_in last * w00, X_in last] with DECODER weights
    {
        const long idx = (long)(b0 + bx) * Lc + (Lc - 1);
        const int   c0 = cat_in[idx];
        const float cc = cont_in[idx];
        const float xx = X_in[idx];
        half8 ax;
        #pragma unroll
        for (int j = 0; j < 8; ++j) ax[j] = (_Float16)0.0f;
        if (q < 2)       ax = *(const half8*)&emb_lds[c0 * EMBc + 8 * q];
        else if (q == 2) { ax[0] = (_Float16)(cc * w00); ax[1] = (_Float16)xx; }
        #pragma unroll
        for (int gt = 0; gt < 4; ++gt) {
            float4v a = {bias_s[gt], bias_s[gt], bias_s[gt], bias_s[gt]};
            acc_pre[gt] = __builtin_amdgcn_mfma_f32_16x16x32_f16(ax, Bf[gt][4], a, 0, 0, 0);
        }
    }
    __syncthreads();

    for (int t = 0; t < DECc; ++t) {
        const _Float16* zr = &z_lds[p][0];
        _Float16*       zw = &z_lds[p ^ 1][0];

        const float muq = mu_lds[q];   // mu(t-1) for this lane's batch (0 at t=0)

        const _Float16* ap = zr + bx * ZS + 8 * q;
        half8 Az[4];
        #pragma unroll
        for (int kt = 0; kt < 4; ++kt) Az[kt] = *(const half8*)(ap + 32 * kt);

        float4v acc[4];
        #pragma unroll
        for (int gt = 0; gt < 4; ++gt) {
            float4v a = acc_pre[gt];
            #pragma unroll
            for (int kt = 0; kt < 4; ++kt)
                a = __builtin_amdgcn_mfma_f32_16x16x32_f16(Az[kt], Bf[gt][kt], a, 0, 0, 0);
            acc[gt] = a;
        }

        // build x(t+1) = [emb(cat_out t), cont_out t, mu slot 0] (mu added via w17 next step)
        {
            half8 ax;
            #pragma unroll
            for (int j = 0; j < 8; ++j) ax[j] = (_Float16)0.0f;
            if (q < 2)       ax = *(const half8*)&emb_lds[(int)catob4[t * 4 + bx] * EMBc + 8 * q];
            else if (q == 2) ax[0] = xo4[t * 4 + bx];
            #pragma unroll
            for (int gt = 0; gt < 4; ++gt) {
                float4v a = {bias_s[gt], bias_s[gt], bias_s[gt], bias_s[gt]};
                acc_pre[gt] = __builtin_amdgcn_mfma_f32_16x16x32_f16(ax, Bf[gt][4], a, 0, 0, 0);
            }
        }

        // gates with mu rank-1 correction
        const float gi = sel4(acc[0], q) + muq * w17_s[0];
        const float gf = sel4(acc[1], q) + muq * w17_s[1];
        const float gg = sel4(acc[2], q) + muq * w17_s[2];
        const float go = sel4(acc[3], q) + muq * w17_s[3];

        const float cn = sigm(gf) * c_reg + sigm(gi) * tanh_(gg);
        c_reg = cn;
        const float hv = sigm(go) * tanh_(cn);
        zw[q * ZS + cell] = (_Float16)hv;
        h32_lds[q * 132 + cell] = hv;

        __syncthreads();

        // heads: 24 dot-products x 16 lanes each (8 strided FMAs + shfl reduce)
        if (tid < 384) {
            const int grp = tid >> 4;       // 0..23, wave-aligned 16-thread groups
            const int l16 = tid & 15;
            const int b   = grp & 3, o = grp >> 2;  // o = 0..5
            float s = 0.0f;
            #pragma unroll
            for (int j = 0; j < 8; ++j) {
                const int k = l16 + 16 * j;
                s += wh_lds[o * Hc + k] * h32_lds[b * 132 + k];
            }
            s += __shfl_xor(s, 1);
            s += __shfl_xor(s, 2);
            s += __shfl_xor(s, 4);
            s += __shfl_xor(s, 8);
            if (l16 == 0) {
                const int gb2 = b0 + b;
                if (o == 0) {
                    const float mu = s + bm0;
                    out[gb2 * DECc + t] = mu;
                    mu_lds[b] = mu;   // feedback for rank-1 correction next step
                } else if (o == 1) {
                    out[65536 + gb2 * DECc + t] = softplus_(s + bs0);
                } else {
                    out[131072 + (gb2 * DECc + t) * 4 + (o - 2)] = s + hb_lds[2 + (o - 2)];
                }
            }
        }
        __syncthreads();
        p ^= 1;
    }
    #undef LOAD_T
    #undef BUILD_X
}

extern "C" void kernel_launch(void* const* d_in, const int* in_sizes, int n_in,
                              void* d_out, int out_size, void* d_ws, size_t ws_size,
                              hipStream_t stream) {
    rnnar_kernel<<<1024 / NBc, NTc, 0, stream>>>(
        (const int*)d_in[0],   (const float*)d_in[1],  (const float*)d_in[2],
        (const int*)d_in[3],   (const float*)d_in[4],  (const float*)d_in[5],
        (const float*)d_in[6],
        (const float*)d_in[7], (const float*)d_in[8],  (const float*)d_in[9],
        (const float*)d_in[10],(const float*)d_in[11], (const float*)d_in[12],
        (const float*)d_in[13],(const float*)d_in[14],
        (const float*)d_in[15],(const float*)d_in[16],
        (const float*)d_in[17],(const float*)d_in[18],
        (float*)d_out);
}